// Round 9
// baseline (257.478 us; speedup 1.0000x reference)
//
#include <hip/hip_runtime.h>
#include <hip/hip_bf16.h>

typedef __attribute__((ext_vector_type(8))) short short8;
typedef __attribute__((ext_vector_type(4))) short short4v;
typedef __attribute__((ext_vector_type(4))) float f32x4;

#define MFMA16(a, b, c) __builtin_amdgcn_mfma_f32_16x16x32_bf16(a, b, c, 0, 0, 0)

// round-to-nearest-even f32 -> bf16 bit pattern
__device__ __forceinline__ short f2bf(float f) {
    union { float f; unsigned u; } v; v.f = f;
    unsigned r = v.u + 0x7fffu + ((v.u >> 16) & 1u);
    return (short)(r >> 16);
}
__device__ __forceinline__ unsigned pack2(float lo, float hi) {
    return ((unsigned)(unsigned short)f2bf(hi) << 16) |
           (unsigned)(unsigned short)f2bf(lo);
}
// async global->LDS, 16B/lane; LDS dest = wave-uniform base + lane*16
__device__ __forceinline__ void gload16(const void* g, void* lds) {
    __builtin_amdgcn_global_load_lds(
        (const __attribute__((address_space(1))) unsigned int*)g,
        (__attribute__((address_space(3))) unsigned int*)lds, 16, 0, 0);
}

// ---------------------------------------------------------------------------
// Kernel 0: convert concatenated [Wq;Wk;Wv] (768x256 f32) to bf16.
// ---------------------------------------------------------------------------
__global__ __launch_bounds__(256) void wconv(
    const float* __restrict__ Wq, const float* __restrict__ Wk,
    const float* __restrict__ Wv, short* __restrict__ Wb)
{
    int e = (blockIdx.x * 256 + threadIdx.x) * 8;
    const float* p = (e < 65536) ? (Wq + e)
                   : (e < 131072) ? (Wk + (e - 65536))
                                  : (Wv + (e - 131072));
    float4 a = *(const float4*)p;
    float4 b = *(const float4*)(p + 4);
    short8 h = { f2bf(a.x), f2bf(a.y), f2bf(a.z), f2bf(a.w),
                 f2bf(b.x), f2bf(b.y), f2bf(b.z), f2bf(b.w) };
    *(short8*)(Wb + e) = h;
}

// ---------------------------------------------------------------------------
// Kernel 1: QKV projection (unchanged, verified r2-r8).
// ---------------------------------------------------------------------------
__global__ __launch_bounds__(256) void qkv_proj(
    const float* __restrict__ x, const short* __restrict__ Wb,
    const float* __restrict__ bq, const float* __restrict__ bk,
    const float* __restrict__ bv,
    short* __restrict__ Qb, short* __restrict__ Kb, short* __restrict__ VTg)
{
    __shared__ short xs[64 * 264];
    __shared__ short wsS[64 * 264];

    const int tid = threadIdx.x;
    const int wid = tid >> 6;
    const int l   = tid & 63;
    const int l15 = l & 15, lg = l >> 4;
    const int r0  = blockIdx.x * 64;
    const int cg  = blockIdx.y;

    {
        const float4* src = (const float4*)(x + (size_t)r0 * 256);
        #pragma unroll
        for (int p = 0; p < 16; ++p) {
            float4 v = src[p * 256 + tid];
            int idx = (p * 256 + tid) * 4;
            int row = idx >> 8, col = idx & 255;
            short4v h = { f2bf(v.x), f2bf(v.y), f2bf(v.z), f2bf(v.w) };
            *(short4v*)&xs[row * 264 + col] = h;
        }
    }

    short8 wreg[8];
    {
        const short8* wsrc = (const short8*)(Wb + (size_t)(cg * 3) * 64 * 256);
        #pragma unroll
        for (int p = 0; p < 8; ++p) wreg[p] = wsrc[p * 256 + tid];
    }
    __syncthreads();

    short8 afr[8];
    {
        const int arow = wid * 16 + l15;
        #pragma unroll
        for (int ks = 0; ks < 8; ++ks)
            afr[ks] = *(const short8*)&xs[arow * 264 + ks * 32 + lg * 8];
    }

    const float* bm[3] = { bq, bk, bv };

    for (int c = 0; c < 3; ++c) {
        const int gc  = cg * 3 + c;
        const int m   = gc >> 2;
        const int wr0 = (gc & 3) * 64;

        #pragma unroll
        for (int p = 0; p < 8; ++p) {
            int idx8 = p * 256 + tid;
            int row = idx8 >> 5, col = (idx8 & 31) * 8;
            *(short8*)&wsS[row * 264 + col] = wreg[p];
        }
        __syncthreads();

        if (c < 2) {
            const short8* wsrc =
                (const short8*)(Wb + (size_t)(gc + 1) * 64 * 256);
            #pragma unroll
            for (int p = 0; p < 8; ++p) wreg[p] = wsrc[p * 256 + tid];
        }

        f32x4 acc[4] = {};
        #pragma unroll
        for (int n = 0; n < 4; ++n) {
            const short* kr = &wsS[(n * 16 + l15) * 264 + lg * 8];
            #pragma unroll
            for (int ks = 0; ks < 8; ++ks) {
                short8 bfr = *(const short8*)(kr + ks * 32);
                acc[n] = MFMA16(afr[ks], bfr, acc[n]);
            }
        }

        const int rowbase = r0 + wid * 16 + (lg << 2);
        #pragma unroll
        for (int n = 0; n < 4; ++n) {
            const int col   = wr0 + n * 16 + l15;
            const float bias = bm[m][col];
            #pragma unroll
            for (int j = 0; j < 4; ++j) {
                const int grow = rowbase + j;
                short hv = f2bf(acc[n][j] + bias);
                if (m == 0)      Qb[(size_t)grow * 256 + col] = hv;
                else if (m == 1) Kb[(size_t)grow * 256 + col] = hv;
                else {
                    int bb = grow >> 12, tt = grow & 4095;
                    VTg[(size_t)bb * (256 * 4096) + (size_t)col * 4096 + tt] = hv;
                }
            }
        }
        __syncthreads();
    }
}

// ---------------------------------------------------------------------------
// Kernel 2: causal flash attention, 32-rows-per-wave (r8 + -inf merge guards).
//   grid 256 (64-row Q tile x 4 batches) x 512 thr = 8 waves (2 rg x 4 par).
//   Wave (rg,par): 32 Q-rows (2 tq x 16), tile kt = 4*si + par, KVBLK = 32.
//   r8 NaN root cause: merge round 1b computed exp(-inf - (-inf)) for waves
//   whose every tile was causally masked (e.g. rowblk=0, par=1, rg=0) --
//   restored the Me guard that r4/r5 had.
// ---------------------------------------------------------------------------
__global__ __launch_bounds__(512, 1) void attn_fwd(
    const short* __restrict__ Qb, const short* __restrict__ Kb,
    const short* __restrict__ VTg, float* __restrict__ out)
{
    // [0,65536)       K tiles [par][32 key][256 d], row 512B, slot s at s^(key&15)
    // [65536,131072)  V tiles [par][256 d][32 key], row 64B,  slot s at s^((d>>1)&3)
    // [131072,151552) Ps: per-wave [32 rows][40 shorts] (stride 80B)
    // epilogue overlay: scr [2][64][260] f32 (133120B) + ms [2][64][2] f32
    __shared__ __attribute__((aligned(16))) char SMEM[151552];
    short* KV = (short*)SMEM;
    short* Ps = (short*)(SMEM + 131072);

    const int tid = threadIdx.x;
    const int wid = tid >> 6;          // 0..7
    const int l   = tid & 63;
    const int l15 = l & 15, lg = l >> 4;
    const int rg  = wid >> 2;          // 0..1 : which 32 rows
    const int par = wid & 3;           // kt-tile parity 0..3

    const int rowblk = blockIdx.x >> 2;    // 0..63 (64-row tiles)
    const int b      = blockIdx.x & 3;
    const int nkt    = 2 * rowblk + 2;     // 32-key tiles
    const int nsi    = (nkt + 3) >> 2;

    const short* KbB = Kb  + (size_t)b * 4096 * 256;
    const short* VTB = VTg + (size_t)b * (256 * 4096);

    const int qrow0 = rowblk * 64 + rg * 32;

    // Q fragments (B-operand): rows qrow0 + tq*16 + l15
    short8 qf[2][8];
    #pragma unroll
    for (int tq = 0; tq < 2; ++tq) {
        const short* qr = Qb + ((size_t)(b * 4096 + qrow0 + tq * 16 + l15)) * 256
                          + lg * 8;
        #pragma unroll
        for (int ks = 0; ks < 8; ++ks)
            qf[tq][ks] = *(const short8*)(qr + ks * 32);
    }

    // DMA staging: wave par<4 -> K[par]; wave par+4 -> V[par]. 16KB per wave.
    auto stage = [&](int si) {
        const int ktt = si * 4 + par;
        if (ktt >= nkt) return;
        if (wid < 4) {
            char* lb = (char*)KV + par * 16384;
            const short* gK = KbB + (size_t)ktt * 32 * 256;
            #pragma unroll
            for (int inst = 0; inst < 16; ++inst) {
                int off  = inst * 1024 + l * 16;            // linear dest byte
                int key  = off >> 9;
                int slot = ((off >> 4) & 31) ^ (key & 15);  // inverse swizzle
                gload16(gK + key * 256 + slot * 8, lb + inst * 1024);
            }
        } else {
            char* lb = (char*)KV + 65536 + par * 16384;
            const short* gV = VTB + ktt * 32;
            #pragma unroll
            for (int inst = 0; inst < 16; ++inst) {
                int off = inst * 1024 + l * 16;
                int d   = off >> 6;
                int s   = ((off >> 4) & 3) ^ ((d >> 1) & 3);
                gload16(gV + (size_t)d * 4096 + s * 8, lb + inst * 1024);
            }
        }
    };
    stage(0);

    f32x4 o[16][2] = {};
    float mrow[2] = { -INFINITY, -INFINITY };
    float srow[2] = { 0.f, 0.f };

    for (int si = 0; si < nsi; ++si) {
        // drain own DMA so every wave's tile is in LDS before anyone crosses
        asm volatile("s_waitcnt vmcnt(0)" ::: "memory");
        __syncthreads();

        const int kt  = si * 4 + par;
        const bool act = (kt < nkt);
        short8 vf2[4], pb[2];
        float  f2[2];

        if (act) {
            // ---- S^T = K * Q : lane holds S[key=tk*16+lg*4+j][qrow l15] ----
            const short* Kt = (const short*)((const char*)KV + par * 16384);
            f32x4 sA[2][2] = {};
            #pragma unroll
            for (int tk = 0; tk < 2; ++tk) {
                const int key = tk * 16 + l15;
                #pragma unroll
                for (int ks = 0; ks < 8; ++ks) {
                    const int slot = (ks * 4 + lg) ^ l15;
                    short8 kf = *(const short8*)(Kt + key * 256 + slot * 8);
                    sA[tk][0] = MFMA16(kf, qf[0][ks], sA[tk][0]);
                    sA[tk][1] = MFMA16(kf, qf[1][ks], sA[tk][1]);
                }
            }

            // ---- scale + causal mask + per-lane softmax (per tq) ----
            float pmax[2] = { -INFINITY, -INFINITY };
            #pragma unroll
            for (int tk = 0; tk < 2; ++tk)
                #pragma unroll
                for (int tq = 0; tq < 2; ++tq) {
                    const int qrow = qrow0 + tq * 16 + l15;
                    #pragma unroll
                    for (int j4 = 0; j4 < 4; ++j4) {
                        const int key = kt * 32 + tk * 16 + lg * 4 + j4;
                        float v = sA[tk][tq][j4] * 0.0625f;   // 1/sqrt(256)
                        v = (key > qrow) ? -INFINITY : v;
                        sA[tk][tq][j4] = v;
                        pmax[tq] = fmaxf(pmax[tq], v);
                    }
                }
            #pragma unroll
            for (int tq = 0; tq < 2; ++tq) {
                pmax[tq] = fmaxf(pmax[tq], __shfl_xor(pmax[tq], 16, 64));
                pmax[tq] = fmaxf(pmax[tq], __shfl_xor(pmax[tq], 32, 64));
            }

            short* Pw = Ps + wid * 1280;       // [32][40] shorts
            #pragma unroll
            for (int tq = 0; tq < 2; ++tq) {
                const float mn  = fmaxf(mrow[tq], pmax[tq]);
                const float mne = (mn == -INFINITY) ? 0.f : mn;  // guard
                f2[tq] = __expf(mrow[tq] - mne);
                mrow[tq] = mn;
                float ps = 0.f;
                #pragma unroll
                for (int tk = 0; tk < 2; ++tk) {
                    float p0 = __expf(sA[tk][tq][0] - mne);
                    float p1 = __expf(sA[tk][tq][1] - mne);
                    float p2 = __expf(sA[tk][tq][2] - mne);
                    float p3 = __expf(sA[tk][tq][3] - mne);
                    ps += (p0 + p1) + (p2 + p3);
                    unsigned* pw = (unsigned*)(Pw + (tq * 16 + l15) * 40 +
                                               tk * 16 + lg * 4);
                    pw[0] = pack2(p0, p1);
                    pw[1] = pack2(p2, p3);
                }
                srow[tq] = srow[tq] * f2[tq] + ps;
            }

            asm volatile("s_waitcnt lgkmcnt(0)" ::: "memory");
            __builtin_amdgcn_sched_barrier(0);

            // B-frags: contiguous keys lg*8..+7 of row tq*16+l15
            #pragma unroll
            for (int tq = 0; tq < 2; ++tq)
                pb[tq] = *(const short8*)(Pw + (tq * 16 + l15) * 40 + lg * 8);

            // ---- PV part 1: dt 0..11 (rescale fused) ----
            const short* Vt = (const short*)((const char*)KV + 65536 +
                                             par * 16384);
            #pragma unroll
            for (int dt = 0; dt < 12; ++dt) {
                #pragma unroll
                for (int tq = 0; tq < 2; ++tq)
                    #pragma unroll
                    for (int j4 = 0; j4 < 4; ++j4) o[dt][tq][j4] *= f2[tq];
                const int d  = dt * 16 + l15;
                const int sx = lg ^ ((d >> 1) & 3);
                short8 va = *(const short8*)(Vt + d * 32 + sx * 8);
                o[dt][0] = MFMA16(va, pb[0], o[dt][0]);
                o[dt][1] = MFMA16(va, pb[1], o[dt][1]);
            }
            // reads for deferred part
            #pragma unroll
            for (int dt = 12; dt < 16; ++dt) {
                const int d  = dt * 16 + l15;
                const int sx = lg ^ ((d >> 1) & 3);
                vf2[dt - 12] = *(const short8*)(Vt + d * 32 + sx * 8);
            }
        }

        __syncthreads();                 // all LDS reads of this si done
        if (si + 1 < nsi) stage(si + 1); // async DMA overwrite
        __builtin_amdgcn_sched_barrier(0);

        if (act) {
            // ---- PV part 2 (register-only; overlaps DMA issue) ----
            #pragma unroll
            for (int dt = 12; dt < 16; ++dt) {
                #pragma unroll
                for (int tq = 0; tq < 2; ++tq)
                    #pragma unroll
                    for (int j4 = 0; j4 < 4; ++j4) o[dt][tq][j4] *= f2[tq];
                o[dt][0] = MFMA16(vf2[dt - 12], pb[0], o[dt][0]);
                o[dt][1] = MFMA16(vf2[dt - 12], pb[1], o[dt][1]);
            }
        }
    }

    // full row sums across the 4 lg lanes of each row
    #pragma unroll
    for (int tq = 0; tq < 2; ++tq) {
        srow[tq] += __shfl_xor(srow[tq], 16, 64);
        srow[tq] += __shfl_xor(srow[tq], 32, 64);
    }

    // ---- 4-way par merge via LDS overlay (2 rounds) ----
    __syncthreads();
    float* scr = (float*)SMEM;                 // [2][64][260] f32
    float* ms  = (float*)(SMEM + 133120);      // [2][64][2]  f32

    // round 1a: par 2,3 dump
    if (par >= 2) {
        const int p = par - 2;
        #pragma unroll
        for (int tq = 0; tq < 2; ++tq) {
            const int rl = rg * 32 + tq * 16 + l15;
            #pragma unroll
            for (int dt = 0; dt < 16; ++dt)
                *(f32x4*)&scr[p * 16640 + rl * 260 + dt * 16 + lg * 4] =
                    o[dt][tq];
            if (lg == 0) {
                ms[p * 128 + rl * 2 + 0] = mrow[tq];
                ms[p * 128 + rl * 2 + 1] = srow[tq];
            }
        }
    }
    __syncthreads();
    // round 1b: par0 += par2, par1 += par3 (Me guard: both can be -inf)
    if (par < 2) {
        #pragma unroll
        for (int tq = 0; tq < 2; ++tq) {
            const int rl = rg * 32 + tq * 16 + l15;
            const float m1 = ms[par * 128 + rl * 2 + 0];
            const float s1 = ms[par * 128 + rl * 2 + 1];
            const float M  = fmaxf(mrow[tq], m1);
            const float Me = (M == -INFINITY) ? 0.f : M;   // guard (r8 bug)
            const float w0 = __expf(mrow[tq] - Me);
            const float w1 = __expf(m1 - Me);
            srow[tq] = srow[tq] * w0 + s1 * w1;
            mrow[tq] = M;
            #pragma unroll
            for (int dt = 0; dt < 16; ++dt) {
                f32x4 o1 = *(f32x4*)&scr[par * 16640 + rl * 260 + dt * 16 +
                                         lg * 4];
                #pragma unroll
                for (int j4 = 0; j4 < 4; ++j4)
                    o[dt][tq][j4] = o[dt][tq][j4] * w0 + o1[j4] * w1;
            }
        }
    }
    __syncthreads();
    // round 2a: par1 dumps merged partial
    if (par == 1) {
        #pragma unroll
        for (int tq = 0; tq < 2; ++tq) {
            const int rl = rg * 32 + tq * 16 + l15;
            #pragma unroll
            for (int dt = 0; dt < 16; ++dt)
                *(f32x4*)&scr[rl * 260 + dt * 16 + lg * 4] = o[dt][tq];
            if (lg == 0) {
                ms[rl * 2 + 0] = mrow[tq];
                ms[rl * 2 + 1] = srow[tq];
            }
        }
    }
    __syncthreads();
    // round 2b: par0 merges, normalizes, stores (par0 mrow always finite,
    // but keep the guard for robustness)
    if (par == 0) {
        #pragma unroll
        for (int tq = 0; tq < 2; ++tq) {
            const int rl = rg * 32 + tq * 16 + l15;
            const float m1 = ms[rl * 2 + 0];
            const float s1 = ms[rl * 2 + 1];
            const float M  = fmaxf(mrow[tq], m1);
            const float Me = (M == -INFINITY) ? 0.f : M;   // guard
            const float w0 = __expf(mrow[tq] - Me);
            const float w1 = __expf(m1 - Me);
            const float rs = 1.f / (srow[tq] * w0 + s1 * w1);
            float* og = out + ((size_t)(b * 4096 + rowblk * 64 + rl)) * 256;
            #pragma unroll
            for (int dt = 0; dt < 16; ++dt) {
                f32x4 o1 = *(f32x4*)&scr[rl * 260 + dt * 16 + lg * 4];
                f32x4 r;
                #pragma unroll
                for (int j4 = 0; j4 < 4; ++j4)
                    r[j4] = (o[dt][tq][j4] * w0 + o1[j4] * w1) * rs;
                *(f32x4*)&og[dt * 16 + lg * 4] = r;
            }
        }
    }
}

// ---------------------------------------------------------------------------
extern "C" void kernel_launch(void* const* d_in, const int* in_sizes, int n_in,
                              void* d_out, int out_size, void* d_ws, size_t ws_size,
                              hipStream_t stream) {
    const float* x  = (const float*)d_in[0];
    const float* Wq = (const float*)d_in[1];
    const float* bq = (const float*)d_in[2];
    const float* Wk = (const float*)d_in[3];
    const float* bk = (const float*)d_in[4];
    const float* Wv = (const float*)d_in[5];
    const float* bv = (const float*)d_in[6];

    short* Qb  = (short*)d_ws;                         // 8 MB
    short* Kb  = Qb + (size_t)16384 * 256;             // 8 MB
    short* VTg = Kb + (size_t)16384 * 256;             // 8 MB
    short* Wb  = VTg + (size_t)4 * 256 * 4096;         // 384 KB
    float* out = (float*)d_out;

    wconv<<<dim3(96), dim3(256), 0, stream>>>(Wq, Wk, Wv, Wb);
    qkv_proj<<<dim3(256, 4), dim3(256), 0, stream>>>(x, Wb, bq, bk, bv,
                                                     Qb, Kb, VTg);
    attn_fwd<<<dim3(256), dim3(512), 0, stream>>>(Qb, Kb, VTg, out);
}

// Round 10
// 161.909 us; speedup vs baseline: 1.5903x; 1.5903x over previous
//
#include <hip/hip_runtime.h>
#include <hip/hip_bf16.h>

typedef __attribute__((ext_vector_type(8))) short short8;
typedef __attribute__((ext_vector_type(4))) short short4v;
typedef __attribute__((ext_vector_type(4))) float f32x4;

#define MFMA16(a, b, c) __builtin_amdgcn_mfma_f32_16x16x32_bf16(a, b, c, 0, 0, 0)

// round-to-nearest-even f32 -> bf16 bit pattern
__device__ __forceinline__ short f2bf(float f) {
    union { float f; unsigned u; } v; v.f = f;
    unsigned r = v.u + 0x7fffu + ((v.u >> 16) & 1u);
    return (short)(r >> 16);
}
__device__ __forceinline__ unsigned pack2(float lo, float hi) {
    return ((unsigned)(unsigned short)f2bf(hi) << 16) |
           (unsigned)(unsigned short)f2bf(lo);
}
// async global->LDS, 16B/lane; LDS dest = wave-uniform base + lane*16
__device__ __forceinline__ void gload16(const void* g, void* lds) {
    __builtin_amdgcn_global_load_lds(
        (const __attribute__((address_space(1))) unsigned int*)g,
        (__attribute__((address_space(3))) unsigned int*)lds, 16, 0, 0);
}

// ---------------------------------------------------------------------------
// Kernel 0: convert concatenated [Wq;Wk;Wv] (768x256 f32) to bf16.
// ---------------------------------------------------------------------------
__global__ __launch_bounds__(256) void wconv(
    const float* __restrict__ Wq, const float* __restrict__ Wk,
    const float* __restrict__ Wv, short* __restrict__ Wb)
{
    int e = (blockIdx.x * 256 + threadIdx.x) * 8;
    const float* p = (e < 65536) ? (Wq + e)
                   : (e < 131072) ? (Wk + (e - 65536))
                                  : (Wv + (e - 131072));
    float4 a = *(const float4*)p;
    float4 b = *(const float4*)(p + 4);
    short8 h = { f2bf(a.x), f2bf(a.y), f2bf(a.z), f2bf(a.w),
                 f2bf(b.x), f2bf(b.y), f2bf(b.z), f2bf(b.w) };
    *(short8*)(Wb + e) = h;
}

// ---------------------------------------------------------------------------
// Kernel 1: QKV projection (unchanged, verified r2-r9).
// ---------------------------------------------------------------------------
__global__ __launch_bounds__(256) void qkv_proj(
    const float* __restrict__ x, const short* __restrict__ Wb,
    const float* __restrict__ bq, const float* __restrict__ bk,
    const float* __restrict__ bv,
    short* __restrict__ Qb, short* __restrict__ Kb, short* __restrict__ VTg)
{
    __shared__ short xs[64 * 264];
    __shared__ short wsS[64 * 264];

    const int tid = threadIdx.x;
    const int wid = tid >> 6;
    const int l   = tid & 63;
    const int l15 = l & 15, lg = l >> 4;
    const int r0  = blockIdx.x * 64;
    const int cg  = blockIdx.y;

    {
        const float4* src = (const float4*)(x + (size_t)r0 * 256);
        #pragma unroll
        for (int p = 0; p < 16; ++p) {
            float4 v = src[p * 256 + tid];
            int idx = (p * 256 + tid) * 4;
            int row = idx >> 8, col = idx & 255;
            short4v h = { f2bf(v.x), f2bf(v.y), f2bf(v.z), f2bf(v.w) };
            *(short4v*)&xs[row * 264 + col] = h;
        }
    }

    short8 wreg[8];
    {
        const short8* wsrc = (const short8*)(Wb + (size_t)(cg * 3) * 64 * 256);
        #pragma unroll
        for (int p = 0; p < 8; ++p) wreg[p] = wsrc[p * 256 + tid];
    }
    __syncthreads();

    short8 afr[8];
    {
        const int arow = wid * 16 + l15;
        #pragma unroll
        for (int ks = 0; ks < 8; ++ks)
            afr[ks] = *(const short8*)&xs[arow * 264 + ks * 32 + lg * 8];
    }

    const float* bm[3] = { bq, bk, bv };

    for (int c = 0; c < 3; ++c) {
        const int gc  = cg * 3 + c;
        const int m   = gc >> 2;
        const int wr0 = (gc & 3) * 64;

        #pragma unroll
        for (int p = 0; p < 8; ++p) {
            int idx8 = p * 256 + tid;
            int row = idx8 >> 5, col = (idx8 & 31) * 8;
            *(short8*)&wsS[row * 264 + col] = wreg[p];
        }
        __syncthreads();

        if (c < 2) {
            const short8* wsrc =
                (const short8*)(Wb + (size_t)(gc + 1) * 64 * 256);
            #pragma unroll
            for (int p = 0; p < 8; ++p) wreg[p] = wsrc[p * 256 + tid];
        }

        f32x4 acc[4] = {};
        #pragma unroll
        for (int n = 0; n < 4; ++n) {
            const short* kr = &wsS[(n * 16 + l15) * 264 + lg * 8];
            #pragma unroll
            for (int ks = 0; ks < 8; ++ks) {
                short8 bfr = *(const short8*)(kr + ks * 32);
                acc[n] = MFMA16(afr[ks], bfr, acc[n]);
            }
        }

        const int rowbase = r0 + wid * 16 + (lg << 2);
        #pragma unroll
        for (int n = 0; n < 4; ++n) {
            const int col   = wr0 + n * 16 + l15;
            const float bias = bm[m][col];
            #pragma unroll
            for (int j = 0; j < 4; ++j) {
                const int grow = rowbase + j;
                short hv = f2bf(acc[n][j] + bias);
                if (m == 0)      Qb[(size_t)grow * 256 + col] = hv;
                else if (m == 1) Kb[(size_t)grow * 256 + col] = hv;
                else {
                    int bb = grow >> 12, tt = grow & 4095;
                    VTg[(size_t)bb * (256 * 4096) + (size_t)col * 4096 + tt] = hv;
                }
            }
        }
        __syncthreads();
    }
}

// ---------------------------------------------------------------------------
// Kernel 2: causal flash attention = r7 (153us champion) with ONE change:
//   global_load_lds DMA staging (r9-verified: explicit vmcnt(0) drain before
//   the loop-top barrier) replaces reg-staging. 512 blocks x 256 thr
//   (4 waves: rg 16-rows x par 2-way kt split), KVBLK=32, 2 blocks/CU
//   (LDS 70KB). Deferred PV part-2 (register-only) covers the DMA issue.
//   Everything else byte-identical to r7's passing text.
// ---------------------------------------------------------------------------
__global__ __launch_bounds__(256, 2) void attn_fwd(
    const short* __restrict__ Qb, const short* __restrict__ Kb,
    const short* __restrict__ VTg, float* __restrict__ out)
{
    // [0,32768)      K tiles [par][32 key][256 d], row 512B, slot s at s^(key&15)
    // [32768,65536)  V tiles [par][256 d][32 key], row 64B,  slot s at s^((d>>1)&3)
    // [65536,71680)  Ps: per-wave [16 rows][48 shorts]
    // epilogue overlay: scr [32][260] f32 + ms [32][2] f32
    __shared__ __attribute__((aligned(16))) char SMEM[71680];
    short* KV = (short*)SMEM;                 // 64 KB
    short* Ps = (short*)(SMEM + 65536);       // 4 x 1536 B

    const int tid = threadIdx.x;
    const int wid = tid >> 6;
    const int l   = tid & 63;
    const int l15 = l & 15, lg = l >> 4;
    const int rg  = wid >> 1;          // 16-row group 0..1
    const int par = wid & 1;           // kt parity

    // XCD-batch swizzle + antithetic heavy/light pairing (r7 verbatim)
    const int bid = blockIdx.x;                  // 0..511
    const int xcd = bid & 7;
    const int b   = xcd & 3, hh = xcd >> 2;
    const int jj  = bid >> 3;                    // 0..63
    const int rowblk = (jj < 32) ? (2 * jj + hh) : (127 - (2 * (jj - 32) + hh));
    const int nkt = rowblk + 1;                  // 32-key tiles
    const int nsi = (nkt + 1) >> 1;

    const short* KbB = Kb  + (size_t)b * 4096 * 256;
    const short* VTB = VTg + (size_t)b * (256 * 4096);

    const int qrow_loc = rg * 16 + l15;
    const int qrow     = rowblk * 32 + qrow_loc;

    // Q fragments (B-operand), row = qrow
    short8 qf[8];
    {
        const short* qr = Qb + ((size_t)(b * 4096 + qrow)) * 256 + lg * 8;
        #pragma unroll
        for (int ks = 0; ks < 8; ++ks)
            qf[ks] = *(const short8*)(qr + ks * 32);
    }

    // DMA staging: waves 0,1 -> K[par]; waves 2,3 -> V[par]. 16KB per wave.
    auto stage = [&](int si) {
        const int ktt = 2 * si + (wid & 1);
        if (ktt >= nkt) return;
        if (wid < 2) {
            char* lb = (char*)SMEM + (wid & 1) * 16384;
            const short* gK = KbB + (size_t)ktt * 32 * 256;
            #pragma unroll
            for (int inst = 0; inst < 16; ++inst) {
                int off  = inst * 1024 + l * 16;            // linear dest byte
                int key  = off >> 9;
                int slot = ((off >> 4) & 31) ^ (key & 15);  // inverse swizzle
                gload16(gK + key * 256 + slot * 8, lb + inst * 1024);
            }
        } else {
            char* lb = (char*)SMEM + 32768 + (wid & 1) * 16384;
            const short* gV = VTB + ktt * 32;
            #pragma unroll
            for (int inst = 0; inst < 16; ++inst) {
                int off = inst * 1024 + l * 16;
                int d   = off >> 6;
                int s   = ((off >> 4) & 3) ^ ((d >> 1) & 3);
                gload16(gV + (size_t)d * 4096 + s * 8, lb + inst * 1024);
            }
        }
    };
    stage(0);

    f32x4 o[16] = {};
    float mrow = -INFINITY, srow = 0.f;

    for (int si = 0; si < nsi; ++si) {
        // drain own DMA, then barrier: all tiles in LDS before anyone reads
        asm volatile("s_waitcnt vmcnt(0)" ::: "memory");
        __syncthreads();

        const int kt  = 2 * si + par;
        const bool act = (kt < nkt);
        short8 vf2[4], pb;
        float  f;

        if (act) {
            // ---- S^T = K * Q : lane holds S[qrow=l15][key=tk*16+lg*4+j] ----
            const short* Kt = (const short*)(SMEM + par * 16384);
            f32x4 sA[2] = {};
            #pragma unroll
            for (int tk = 0; tk < 2; ++tk) {
                const int key = tk * 16 + l15;
                #pragma unroll
                for (int ks = 0; ks < 8; ++ks) {
                    const int slot = (ks * 4 + lg) ^ l15;
                    short8 kf = *(const short8*)(Kt + key * 256 + slot * 8);
                    sA[tk] = MFMA16(kf, qf[ks], sA[tk]);
                }
            }

            // ---- scale + causal mask + per-lane softmax ----
            float pmax = -INFINITY;
            #pragma unroll
            for (int tk = 0; tk < 2; ++tk)
                #pragma unroll
                for (int j4 = 0; j4 < 4; ++j4) {
                    const int key = kt * 32 + tk * 16 + lg * 4 + j4;
                    float v = sA[tk][j4] * 0.0625f;       // 1/sqrt(256)
                    v = (key > qrow) ? -INFINITY : v;
                    sA[tk][j4] = v;
                    pmax = fmaxf(pmax, v);
                }
            pmax = fmaxf(pmax, __shfl_xor(pmax, 16, 64));
            pmax = fmaxf(pmax, __shfl_xor(pmax, 32, 64));

            const float mn  = fmaxf(mrow, pmax);
            const float mne = (mn == -INFINITY) ? 0.f : mn;   // guard
            f = __expf(mrow - mne);                           // 0 on first tile
            mrow = mn;

            // P = exp(s - m): scatter to Ps[row=l15][key]
            short* Pw = Ps + wid * 768;        // [16][48] shorts
            float ps = 0.f;
            #pragma unroll
            for (int tk = 0; tk < 2; ++tk) {
                float p0 = __expf(sA[tk][0] - mne);
                float p1 = __expf(sA[tk][1] - mne);
                float p2 = __expf(sA[tk][2] - mne);
                float p3 = __expf(sA[tk][3] - mne);
                ps += (p0 + p1) + (p2 + p3);
                unsigned* pw = (unsigned*)(Pw + l15 * 48 + tk * 16 + lg * 4);
                pw[0] = pack2(p0, p1);
                pw[1] = pack2(p2, p3);
            }
            srow = srow * f + ps;

            asm volatile("s_waitcnt lgkmcnt(0)" ::: "memory");
            __builtin_amdgcn_sched_barrier(0);

            // B-frag: contiguous keys lg*8..+7 of row l15 (same map as A=V)
            pb = *(const short8*)(Pw + l15 * 48 + lg * 8);

            // ---- PV part 1: dt 0..11 (rescale fused) ----
            const short* Vt = (const short*)(SMEM + 32768 + par * 16384);
            #pragma unroll
            for (int dt = 0; dt < 12; ++dt) {
                #pragma unroll
                for (int j4 = 0; j4 < 4; ++j4) o[dt][j4] *= f;
                const int d  = dt * 16 + l15;
                const int sx = lg ^ ((d >> 1) & 3);
                short8 va = *(const short8*)(Vt + d * 32 + sx * 8);
                o[dt] = MFMA16(va, pb, o[dt]);
            }
            // reads for deferred part
            #pragma unroll
            for (int dt = 12; dt < 16; ++dt) {
                const int d  = dt * 16 + l15;
                const int sx = lg ^ ((d >> 1) & 3);
                vf2[dt - 12] = *(const short8*)(Vt + d * 32 + sx * 8);
            }
        }

        __syncthreads();                 // all LDS reads of this si done
        if (si + 1 < nsi) stage(si + 1); // async DMA overwrite
        __builtin_amdgcn_sched_barrier(0);

        if (act) {
            // ---- PV part 2 (register-only; overlaps DMA issue/flight) ----
            #pragma unroll
            for (int dt = 12; dt < 16; ++dt) {
                #pragma unroll
                for (int j4 = 0; j4 < 4; ++j4) o[dt][j4] *= f;
                o[dt] = MFMA16(vf2[dt - 12], pb, o[dt]);
            }
        }
    }

    // full row sums across the 4 lg lanes of each row
    srow += __shfl_xor(srow, 16, 64);
    srow += __shfl_xor(srow, 32, 64);

    // ---- 2-way parity merge via LDS overlay (r7 verbatim) ----
    __syncthreads();
    float* scr = (float*)SMEM;                 // [32][260] f32 = 33280 B
    float* ms  = (float*)(SMEM + 33280);       // [32][2]   f32

    if (par == 1) {
        #pragma unroll
        for (int dt = 0; dt < 16; ++dt)
            *(f32x4*)&scr[qrow_loc * 260 + dt * 16 + lg * 4] = o[dt];
        if (lg == 0) {
            ms[qrow_loc * 2 + 0] = mrow;
            ms[qrow_loc * 2 + 1] = srow;
        }
    }
    __syncthreads();
    if (par == 0) {
        const float m1 = ms[qrow_loc * 2 + 0];
        const float s1 = ms[qrow_loc * 2 + 1];
        const float M  = fmaxf(mrow, m1);      // mrow finite (par0 owns tile 0)
        const float w0 = __expf(mrow - M);
        const float w1 = __expf(m1 - M);
        const float rs = 1.f / (srow * w0 + s1 * w1);
        float* og = out + ((size_t)(b * 4096 + qrow)) * 256;
        #pragma unroll
        for (int dt = 0; dt < 16; ++dt) {
            f32x4 o1 = *(f32x4*)&scr[qrow_loc * 260 + dt * 16 + lg * 4];
            f32x4 r;
            #pragma unroll
            for (int j4 = 0; j4 < 4; ++j4)
                r[j4] = (o[dt][j4] * w0 + o1[j4] * w1) * rs;
            *(f32x4*)&og[dt * 16 + lg * 4] = r;
        }
    }
}

// ---------------------------------------------------------------------------
extern "C" void kernel_launch(void* const* d_in, const int* in_sizes, int n_in,
                              void* d_out, int out_size, void* d_ws, size_t ws_size,
                              hipStream_t stream) {
    const float* x  = (const float*)d_in[0];
    const float* Wq = (const float*)d_in[1];
    const float* bq = (const float*)d_in[2];
    const float* Wk = (const float*)d_in[3];
    const float* bk = (const float*)d_in[4];
    const float* Wv = (const float*)d_in[5];
    const float* bv = (const float*)d_in[6];

    short* Qb  = (short*)d_ws;                         // 8 MB
    short* Kb  = Qb + (size_t)16384 * 256;             // 8 MB
    short* VTg = Kb + (size_t)16384 * 256;             // 8 MB
    short* Wb  = VTg + (size_t)4 * 256 * 4096;         // 384 KB
    float* out = (float*)d_out;

    wconv<<<dim3(96), dim3(256), 0, stream>>>(Wq, Wk, Wv, Wb);
    qkv_proj<<<dim3(256, 4), dim3(256), 0, stream>>>(x, Wb, bq, bk, bv,
                                                     Qb, Kb, VTg);
    attn_fwd<<<dim3(512), dim3(256), 0, stream>>>(Qb, Kb, VTg, out);
}

// Round 11
// 144.729 us; speedup vs baseline: 1.7790x; 1.1187x over previous
//
#include <hip/hip_runtime.h>
#include <hip/hip_bf16.h>

typedef __attribute__((ext_vector_type(8))) short short8;
typedef __attribute__((ext_vector_type(4))) short short4v;
typedef __attribute__((ext_vector_type(4))) float f32x4;

#define MFMA16(a, b, c) __builtin_amdgcn_mfma_f32_16x16x32_bf16(a, b, c, 0, 0, 0)

// round-to-nearest-even f32 -> bf16 bit pattern
__device__ __forceinline__ short f2bf(float f) {
    union { float f; unsigned u; } v; v.f = f;
    unsigned r = v.u + 0x7fffu + ((v.u >> 16) & 1u);
    return (short)(r >> 16);
}
__device__ __forceinline__ unsigned pack2(float lo, float hi) {
    return ((unsigned)(unsigned short)f2bf(hi) << 16) |
           (unsigned)(unsigned short)f2bf(lo);
}
// async global->LDS, 16B/lane; LDS dest = wave-uniform base + lane*16
__device__ __forceinline__ void gload16(const void* g, void* lds) {
    __builtin_amdgcn_global_load_lds(
        (const __attribute__((address_space(1))) unsigned int*)g,
        (__attribute__((address_space(3))) unsigned int*)lds, 16, 0, 0);
}

// ---------------------------------------------------------------------------
// Kernel 0: convert concatenated [Wq;Wk;Wv] (768x256 f32) to bf16.
// ---------------------------------------------------------------------------
__global__ __launch_bounds__(256) void wconv(
    const float* __restrict__ Wq, const float* __restrict__ Wk,
    const float* __restrict__ Wv, short* __restrict__ Wb)
{
    int e = (blockIdx.x * 256 + threadIdx.x) * 8;
    const float* p = (e < 65536) ? (Wq + e)
                   : (e < 131072) ? (Wk + (e - 65536))
                                  : (Wv + (e - 131072));
    float4 a = *(const float4*)p;
    float4 b = *(const float4*)(p + 4);
    short8 h = { f2bf(a.x), f2bf(a.y), f2bf(a.z), f2bf(a.w),
                 f2bf(b.x), f2bf(b.y), f2bf(b.z), f2bf(b.w) };
    *(short8*)(Wb + e) = h;
}

// ---------------------------------------------------------------------------
// Kernel 1: QKV projection (unchanged, verified r2-r10).
// ---------------------------------------------------------------------------
__global__ __launch_bounds__(256) void qkv_proj(
    const float* __restrict__ x, const short* __restrict__ Wb,
    const float* __restrict__ bq, const float* __restrict__ bk,
    const float* __restrict__ bv,
    short* __restrict__ Qb, short* __restrict__ Kb, short* __restrict__ VTg)
{
    __shared__ short xs[64 * 264];
    __shared__ short wsS[64 * 264];

    const int tid = threadIdx.x;
    const int wid = tid >> 6;
    const int l   = tid & 63;
    const int l15 = l & 15, lg = l >> 4;
    const int r0  = blockIdx.x * 64;
    const int cg  = blockIdx.y;

    {
        const float4* src = (const float4*)(x + (size_t)r0 * 256);
        #pragma unroll
        for (int p = 0; p < 16; ++p) {
            float4 v = src[p * 256 + tid];
            int idx = (p * 256 + tid) * 4;
            int row = idx >> 8, col = idx & 255;
            short4v h = { f2bf(v.x), f2bf(v.y), f2bf(v.z), f2bf(v.w) };
            *(short4v*)&xs[row * 264 + col] = h;
        }
    }

    short8 wreg[8];
    {
        const short8* wsrc = (const short8*)(Wb + (size_t)(cg * 3) * 64 * 256);
        #pragma unroll
        for (int p = 0; p < 8; ++p) wreg[p] = wsrc[p * 256 + tid];
    }
    __syncthreads();

    short8 afr[8];
    {
        const int arow = wid * 16 + l15;
        #pragma unroll
        for (int ks = 0; ks < 8; ++ks)
            afr[ks] = *(const short8*)&xs[arow * 264 + ks * 32 + lg * 8];
    }

    const float* bm[3] = { bq, bk, bv };

    for (int c = 0; c < 3; ++c) {
        const int gc  = cg * 3 + c;
        const int m   = gc >> 2;
        const int wr0 = (gc & 3) * 64;

        #pragma unroll
        for (int p = 0; p < 8; ++p) {
            int idx8 = p * 256 + tid;
            int row = idx8 >> 5, col = (idx8 & 31) * 8;
            *(short8*)&wsS[row * 264 + col] = wreg[p];
        }
        __syncthreads();

        if (c < 2) {
            const short8* wsrc =
                (const short8*)(Wb + (size_t)(gc + 1) * 64 * 256);
            #pragma unroll
            for (int p = 0; p < 8; ++p) wreg[p] = wsrc[p * 256 + tid];
        }

        f32x4 acc[4] = {};
        #pragma unroll
        for (int n = 0; n < 4; ++n) {
            const short* kr = &wsS[(n * 16 + l15) * 264 + lg * 8];
            #pragma unroll
            for (int ks = 0; ks < 8; ++ks) {
                short8 bfr = *(const short8*)(kr + ks * 32);
                acc[n] = MFMA16(afr[ks], bfr, acc[n]);
            }
        }

        const int rowbase = r0 + wid * 16 + (lg << 2);
        #pragma unroll
        for (int n = 0; n < 4; ++n) {
            const int col   = wr0 + n * 16 + l15;
            const float bias = bm[m][col];
            #pragma unroll
            for (int j = 0; j < 4; ++j) {
                const int grow = rowbase + j;
                short hv = f2bf(acc[n][j] + bias);
                if (m == 0)      Qb[(size_t)grow * 256 + col] = hv;
                else if (m == 1) Kb[(size_t)grow * 256 + col] = hv;
                else {
                    int bb = grow >> 12, tt = grow & 4095;
                    VTg[(size_t)bb * (256 * 4096) + (size_t)col * 4096 + tt] = hv;
                }
            }
        }
        __syncthreads();
    }
}

// ---------------------------------------------------------------------------
// Kernel 2: causal flash attention.
//   512 blocks x 512 thr = 8 waves (2 rg x 4 par), 32 Q-rows/block,
//   16 rows/wave (per-wave state = r10's 104 VGPR, under the 128 cap).
//   4-way par split -> heaviest block 32 steps (vs r10's 64); 8 waves =
//   2 waves/SIMD for the whole block lifetime. LPT dispatch (heaviest
//   rowblk first) backfills 512 blocks over 256 CUs (~33 steps/CU).
//   DMA staging + explicit vmcnt(0) drain (r9/r10-verified); 4-way merge
//   with -inf guards (r9-verified).
// ---------------------------------------------------------------------------
__global__ __launch_bounds__(512, 1) void attn_fwd(
    const short* __restrict__ Qb, const short* __restrict__ Kb,
    const short* __restrict__ VTg, float* __restrict__ out)
{
    // [0,65536)        K tiles [par][32 key][256 d], row 512B, slot s at s^(key&15)
    // [65536,131072)   V tiles [par][256 d][32 key], row 64B,  slot s at s^((d>>1)&3)
    // [131072,143360)  Ps: per-wave [16 rows][48 shorts]
    // epilogue overlay: scr [2][32][260] f32 + ms [2][32][2] f32
    __shared__ __attribute__((aligned(16))) char SMEM[143360];
    short* Ps = (short*)(SMEM + 131072);

    const int tid = threadIdx.x;
    const int wid = tid >> 6;          // 0..7
    const int l   = tid & 63;
    const int l15 = l & 15, lg = l >> 4;
    const int rg  = wid >> 2;          // 0..1 : which 16 rows
    const int par = wid & 3;           // kt-tile parity 0..3

    // LPT decode: heaviest row-blocks dispatched first
    const int bid    = blockIdx.x;             // 0..511
    const int rowblk = 127 - (bid >> 2);       // 32-row tiles, heavy first
    const int b      = bid & 3;
    const int nkt    = rowblk + 1;             // 32-key tiles
    const int nsi    = (nkt + 3) >> 2;

    const short* KbB = Kb  + (size_t)b * 4096 * 256;
    const short* VTB = VTg + (size_t)b * (256 * 4096);

    const int qrow_loc = rg * 16 + l15;
    const int qrow     = rowblk * 32 + qrow_loc;

    // Q fragments (B-operand), row = qrow
    short8 qf[8];
    {
        const short* qr = Qb + ((size_t)(b * 4096 + qrow)) * 256 + lg * 8;
        #pragma unroll
        for (int ks = 0; ks < 8; ++ks)
            qf[ks] = *(const short8*)(qr + ks * 32);
    }

    // DMA staging: wave wid<4 -> K[wid&3]; wid>=4 -> V[wid&3]. 16KB/wave.
    auto stage = [&](int si) {
        const int ktt = si * 4 + (wid & 3);
        if (ktt >= nkt) return;
        if (wid < 4) {
            char* lb = SMEM + (wid & 3) * 16384;
            const short* gK = KbB + (size_t)ktt * 32 * 256;
            #pragma unroll
            for (int inst = 0; inst < 16; ++inst) {
                int off  = inst * 1024 + l * 16;            // linear dest byte
                int key  = off >> 9;
                int slot = ((off >> 4) & 31) ^ (key & 15);  // inverse swizzle
                gload16(gK + key * 256 + slot * 8, lb + inst * 1024);
            }
        } else {
            char* lb = SMEM + 65536 + (wid & 3) * 16384;
            const short* gV = VTB + ktt * 32;
            #pragma unroll
            for (int inst = 0; inst < 16; ++inst) {
                int off = inst * 1024 + l * 16;
                int d   = off >> 6;
                int s   = ((off >> 4) & 3) ^ ((d >> 1) & 3);
                gload16(gV + (size_t)d * 4096 + s * 8, lb + inst * 1024);
            }
        }
    };
    stage(0);

    f32x4 o[16] = {};
    float mrow = -INFINITY, srow = 0.f;

    for (int si = 0; si < nsi; ++si) {
        // drain own DMA, then barrier: all tiles in LDS before anyone reads
        asm volatile("s_waitcnt vmcnt(0)" ::: "memory");
        __syncthreads();

        const int kt  = si * 4 + par;
        const bool act = (kt < nkt);
        short8 vf2[4], pb;
        float  f;

        if (act) {
            // ---- S^T = K * Q : lane holds S[qrow=l15][key=tk*16+lg*4+j] ----
            const short* Kt = (const short*)(SMEM + par * 16384);
            f32x4 sA[2] = {};
            #pragma unroll
            for (int tk = 0; tk < 2; ++tk) {
                const int key = tk * 16 + l15;
                #pragma unroll
                for (int ks = 0; ks < 8; ++ks) {
                    const int slot = (ks * 4 + lg) ^ l15;
                    short8 kf = *(const short8*)(Kt + key * 256 + slot * 8);
                    sA[tk] = MFMA16(kf, qf[ks], sA[tk]);
                }
            }

            // ---- scale + causal mask + per-lane softmax ----
            float pmax = -INFINITY;
            #pragma unroll
            for (int tk = 0; tk < 2; ++tk)
                #pragma unroll
                for (int j4 = 0; j4 < 4; ++j4) {
                    const int key = kt * 32 + tk * 16 + lg * 4 + j4;
                    float v = sA[tk][j4] * 0.0625f;       // 1/sqrt(256)
                    v = (key > qrow) ? -INFINITY : v;
                    sA[tk][j4] = v;
                    pmax = fmaxf(pmax, v);
                }
            pmax = fmaxf(pmax, __shfl_xor(pmax, 16, 64));
            pmax = fmaxf(pmax, __shfl_xor(pmax, 32, 64));

            const float mn  = fmaxf(mrow, pmax);   // active => pmax finite
            const float mne = (mn == -INFINITY) ? 0.f : mn;   // guard
            f = __expf(mrow - mne);                           // 0 on first tile
            mrow = mn;

            // P = exp(s - m): scatter to Ps[row=l15][key]
            short* Pw = Ps + wid * 768;        // [16][48] shorts
            float ps = 0.f;
            #pragma unroll
            for (int tk = 0; tk < 2; ++tk) {
                float p0 = __expf(sA[tk][0] - mne);
                float p1 = __expf(sA[tk][1] - mne);
                float p2 = __expf(sA[tk][2] - mne);
                float p3 = __expf(sA[tk][3] - mne);
                ps += (p0 + p1) + (p2 + p3);
                unsigned* pw = (unsigned*)(Pw + l15 * 48 + tk * 16 + lg * 4);
                pw[0] = pack2(p0, p1);
                pw[1] = pack2(p2, p3);
            }
            srow = srow * f + ps;

            asm volatile("s_waitcnt lgkmcnt(0)" ::: "memory");
            __builtin_amdgcn_sched_barrier(0);

            // B-frag: contiguous keys lg*8..+7 of row l15 (same map as A=V)
            pb = *(const short8*)(Pw + l15 * 48 + lg * 8);

            // ---- PV part 1: dt 0..11 (rescale fused) ----
            const short* Vt = (const short*)(SMEM + 65536 + par * 16384);
            #pragma unroll
            for (int dt = 0; dt < 12; ++dt) {
                #pragma unroll
                for (int j4 = 0; j4 < 4; ++j4) o[dt][j4] *= f;
                const int d  = dt * 16 + l15;
                const int sx = lg ^ ((d >> 1) & 3);
                short8 va = *(const short8*)(Vt + d * 32 + sx * 8);
                o[dt] = MFMA16(va, pb, o[dt]);
            }
            // reads for deferred part
            #pragma unroll
            for (int dt = 12; dt < 16; ++dt) {
                const int d  = dt * 16 + l15;
                const int sx = lg ^ ((d >> 1) & 3);
                vf2[dt - 12] = *(const short8*)(Vt + d * 32 + sx * 8);
            }
        }

        __syncthreads();                 // all LDS reads of this si done
        if (si + 1 < nsi) stage(si + 1); // async DMA overwrite
        __builtin_amdgcn_sched_barrier(0);

        if (act) {
            // ---- PV part 2 (register-only; overlaps DMA issue/flight) ----
            #pragma unroll
            for (int dt = 12; dt < 16; ++dt) {
                #pragma unroll
                for (int j4 = 0; j4 < 4; ++j4) o[dt][j4] *= f;
                o[dt] = MFMA16(vf2[dt - 12], pb, o[dt]);
            }
        }
    }

    // full row sums across the 4 lg lanes of each row
    srow += __shfl_xor(srow, 16, 64);
    srow += __shfl_xor(srow, 32, 64);

    // ---- 4-way par merge via LDS overlay (r9-verified, 32-row geometry) ----
    __syncthreads();
    float* scr = (float*)SMEM;                 // [2][32][260] f32 = 66560 B
    float* ms  = (float*)(SMEM + 66560);       // [2][32][2]  f32

    const int rl = rg * 16 + l15;              // 0..31

    // round 1a: par 2,3 dump
    if (par >= 2) {
        const int p = par - 2;
        #pragma unroll
        for (int dt = 0; dt < 16; ++dt)
            *(f32x4*)&scr[p * 8320 + rl * 260 + dt * 16 + lg * 4] = o[dt];
        if (lg == 0) {
            ms[p * 64 + rl * 2 + 0] = mrow;
            ms[p * 64 + rl * 2 + 1] = srow;
        }
    }
    __syncthreads();
    // round 1b: par0 += par2, par1 += par3 (Me guard: both can be -inf)
    if (par < 2) {
        const float m1 = ms[par * 64 + rl * 2 + 0];
        const float s1 = ms[par * 64 + rl * 2 + 1];
        const float M  = fmaxf(mrow, m1);
        const float Me = (M == -INFINITY) ? 0.f : M;   // guard
        const float w0 = __expf(mrow - Me);
        const float w1 = __expf(m1 - Me);
        srow = srow * w0 + s1 * w1;
        mrow = M;
        #pragma unroll
        for (int dt = 0; dt < 16; ++dt) {
            f32x4 o1 = *(f32x4*)&scr[par * 8320 + rl * 260 + dt * 16 + lg * 4];
            #pragma unroll
            for (int j4 = 0; j4 < 4; ++j4)
                o[dt][j4] = o[dt][j4] * w0 + o1[j4] * w1;
        }
    }
    __syncthreads();
    // round 2a: par1 dumps merged partial
    if (par == 1) {
        #pragma unroll
        for (int dt = 0; dt < 16; ++dt)
            *(f32x4*)&scr[rl * 260 + dt * 16 + lg * 4] = o[dt];
        if (lg == 0) {
            ms[rl * 2 + 0] = mrow;
            ms[rl * 2 + 1] = srow;
        }
    }
    __syncthreads();
    // round 2b: par0 merges, normalizes, stores
    if (par == 0) {
        const float m1 = ms[rl * 2 + 0];
        const float s1 = ms[rl * 2 + 1];
        const float M  = fmaxf(mrow, m1);      // par0 owns tile 0 -> finite
        const float Me = (M == -INFINITY) ? 0.f : M;   // guard anyway
        const float w0 = __expf(mrow - Me);
        const float w1 = __expf(m1 - Me);
        const float rs = 1.f / (srow * w0 + s1 * w1);
        float* og = out + ((size_t)(b * 4096 + rowblk * 32 + rl)) * 256;
        #pragma unroll
        for (int dt = 0; dt < 16; ++dt) {
            f32x4 o1 = *(f32x4*)&scr[rl * 260 + dt * 16 + lg * 4];
            f32x4 r;
            #pragma unroll
            for (int j4 = 0; j4 < 4; ++j4)
                r[j4] = (o[dt][j4] * w0 + o1[j4] * w1) * rs;
            *(f32x4*)&og[dt * 16 + lg * 4] = r;
        }
    }
}

// ---------------------------------------------------------------------------
extern "C" void kernel_launch(void* const* d_in, const int* in_sizes, int n_in,
                              void* d_out, int out_size, void* d_ws, size_t ws_size,
                              hipStream_t stream) {
    const float* x  = (const float*)d_in[0];
    const float* Wq = (const float*)d_in[1];
    const float* bq = (const float*)d_in[2];
    const float* Wk = (const float*)d_in[3];
    const float* bk = (const float*)d_in[4];
    const float* Wv = (const float*)d_in[5];
    const float* bv = (const float*)d_in[6];

    short* Qb  = (short*)d_ws;                         // 8 MB
    short* Kb  = Qb + (size_t)16384 * 256;             // 8 MB
    short* VTg = Kb + (size_t)16384 * 256;             // 8 MB
    short* Wb  = VTg + (size_t)4 * 256 * 4096;         // 384 KB
    float* out = (float*)d_out;

    wconv<<<dim3(96), dim3(256), 0, stream>>>(Wq, Wk, Wv, Wb);
    qkv_proj<<<dim3(256, 4), dim3(256), 0, stream>>>(x, Wb, bq, bk, bv,
                                                     Qb, Kb, VTg);
    attn_fwd<<<dim3(512), dim3(512), 0, stream>>>(Qb, Kb, VTg, out);
}